// Round 8
// baseline (119.220 us; speedup 1.0000x reference)
//
#include <hip/hip_runtime.h>
#include <hip/hip_bf16.h>
#include <cstddef>
#include <cstdint>

#define BATCH 4
#define CDIM 256
#define HW 4096
#define MCTX 1024
#define CTX 256
#define HEADS 8
#define DHEAD 64
#define INNER 512

typedef __attribute__((ext_vector_type(8))) short bf16x8;
typedef __attribute__((ext_vector_type(4))) short bf16x4;
typedef __attribute__((ext_vector_type(4))) float f32x4;

static __device__ __forceinline__ ushort f2bf(float f) {
  __hip_bfloat16 h = __float2bfloat16(f);
  return *reinterpret_cast<ushort*>(&h);
}

// 16x16x16 bf16 MFMA (A regs=2, B regs=2, C/D=4). Builtin if present, else asm.
static __device__ __forceinline__ f32x4 mfma16(bf16x4 a, bf16x4 b, f32x4 c) {
#if __has_builtin(__builtin_amdgcn_mfma_f32_16x16x16bf16_1k)
  return __builtin_amdgcn_mfma_f32_16x16x16bf16_1k(a, b, c, 0, 0, 0);
#else
  asm volatile("v_mfma_f32_16x16x16_bf16 %0, %1, %2, %0"
               : "+v"(c) : "v"(a), "v"(b));
  return c;
#endif
}

// async global->LDS, 16B per lane. LDS dest is wave-uniform base + lane*16.
static __device__ __forceinline__ void gload16(const void* g, void* l) {
  __builtin_amdgcn_global_load_lds(
      (const __attribute__((address_space(1))) void*)(uintptr_t)g,
      (__attribute__((address_space(3))) void*)(uint32_t)(uintptr_t)l,
      16, 0, 0);
}

// ---------------------------------------------------------------------------
// LN over channels of x with layout transpose. x:[b,256,4096] -> xn:[b,4096,256]
// Load phase vectorized: float4 per lane along n (G13).
// ---------------------------------------------------------------------------
__global__ __launch_bounds__(256) void ln_x_kernel(
    const float* __restrict__ x, const float* __restrict__ g,
    const float* __restrict__ bta, float* __restrict__ xn,
    ushort* __restrict__ xnbf) {
  const int blk = blockIdx.x;
  const int bi = blk / (HW / 32);
  const int n0 = (blk % (HW / 32)) * 32;
  __shared__ float xt[32][257];
  __shared__ float smu[32], srs[32];
  const int t = threadIdx.x;
  const float* xb = x + (size_t)bi * CDIM * HW;
  {
    const int cr = t >> 3;            // c within pass (32 per pass)
    const int n4 = (t & 7) * 4;       // 8 lanes x float4 cover 32 n
    #pragma unroll
    for (int pass = 0; pass < 8; ++pass) {
      const int c = pass * 32 + cr;
      float4 v = *(const float4*)(xb + (size_t)c * HW + n0 + n4);
      xt[n4 + 0][c] = v.x; xt[n4 + 1][c] = v.y;
      xt[n4 + 2][c] = v.z; xt[n4 + 3][c] = v.w;
    }
  }
  __syncthreads();
  const int col = t >> 3, j = t & 7;
  float s = 0.f, ss = 0.f;
  #pragma unroll
  for (int c = j; c < CDIM; c += 8) {
    float v = xt[col][c];
    s += v; ss += v * v;
  }
  #pragma unroll
  for (int off = 1; off < 8; off <<= 1) {
    s += __shfl_xor(s, off);
    ss += __shfl_xor(ss, off);
  }
  if (j == 0) {
    float mu = s * (1.f / CDIM);
    smu[col] = mu;
    srs[col] = rsqrtf(ss * (1.f / CDIM) - mu * mu + 1e-5f);
  }
  __syncthreads();
  const float gv = g[t], bvv = bta[t];
  float* xnb = xn + ((size_t)bi * HW + n0) * CDIM;
  ushort* xbb = xnbf + ((size_t)bi * HW + n0) * CDIM;
  #pragma unroll 4
  for (int n = 0; n < 32; ++n) {
    float val = (xt[n][t] - smu[n]) * srs[n] * gv + bvv;
    xnb[(size_t)n * CDIM + t] = val;
    xbb[(size_t)n * CDIM + t] = f2bf(val);
  }
}

// ---------------------------------------------------------------------------
// LN y rows -> bf16. 4 waves per block, one row each.
// ---------------------------------------------------------------------------
__global__ __launch_bounds__(256) void ln_y_kernel(
    const float* __restrict__ y, const float* __restrict__ g,
    const float* __restrict__ bta, ushort* __restrict__ ynbf) {
  const int row = blockIdx.x * 4 + (threadIdx.x >> 6);
  const int t = threadIdx.x & 63;
  float4 v = ((const float4*)(y + (size_t)row * CTX))[t];
  float s = v.x + v.y + v.z + v.w;
  float ss = v.x * v.x + v.y * v.y + v.z * v.z + v.w * v.w;
  #pragma unroll
  for (int off = 1; off < 64; off <<= 1) {
    s += __shfl_xor(s, off);
    ss += __shfl_xor(ss, off);
  }
  float mu = s * (1.f / CTX);
  float rs = rsqrtf(ss * (1.f / CTX) - mu * mu + 1e-5f);
  float4 gv = ((const float4*)g)[t];
  float4 b4 = ((const float4*)bta)[t];
  ushort4 ob;
  ob.x = f2bf((v.x - mu) * rs * gv.x + b4.x);
  ob.y = f2bf((v.y - mu) * rs * gv.y + b4.y);
  ob.z = f2bf((v.z - mu) * rs * gv.z + b4.z);
  ob.w = f2bf((v.w - mu) * rs * gv.w + b4.w);
  *(ushort4*)(ynbf + (size_t)row * CTX + t * 4) = ob;
}

// ---------------------------------------------------------------------------
// Weight prep: W [K][N] fp32 -> Wt [N][K] bf16 (64x64 LDS transpose tiles)
// ---------------------------------------------------------------------------
static __device__ __forceinline__ void wprep_body(
    const float* __restrict__ W, ushort* __restrict__ Wt, int K, int N) {
  __shared__ ushort T[64][65];
  const int k0 = blockIdx.y * 64, n0 = blockIdx.x * 64;
  const int t = threadIdx.x;
  #pragma unroll
  for (int rr = 0; rr < 4; ++rr) {
    int row = rr * 16 + (t >> 4);          // k
    int c = (t & 15) * 4;                  // n
    float4 wv = *(const float4*)(W + (size_t)(k0 + row) * N + n0 + c);
    T[row][c + 0] = f2bf(wv.x); T[row][c + 1] = f2bf(wv.y);
    T[row][c + 2] = f2bf(wv.z); T[row][c + 3] = f2bf(wv.w);
  }
  __syncthreads();
  #pragma unroll
  for (int rr = 0; rr < 4; ++rr) {
    int nrow = rr * 16 + (t >> 4);
    int kc = (t & 15) * 4;
    ushort4 o;
    o.x = T[kc + 0][nrow]; o.y = T[kc + 1][nrow];
    o.z = T[kc + 2][nrow]; o.w = T[kc + 3][nrow];
    *(ushort4*)(Wt + (size_t)(n0 + nrow) * K + k0 + kc) = o;
  }
}

__global__ __launch_bounds__(256) void wprep3_kernel(
    const float* __restrict__ W0, const float* __restrict__ W1,
    const float* __restrict__ W2, ushort* __restrict__ T0,
    ushort* __restrict__ T1, ushort* __restrict__ T2) {
  const int z = blockIdx.z;
  const float* W = (z == 0) ? W0 : (z == 1) ? W1 : W2;
  ushort* Wt = (z == 0) ? T0 : (z == 1) ? T1 : T2;
  wprep_body(W, Wt, 256, 512);
}

__global__ __launch_bounds__(256) void wprep_kernel(
    const float* __restrict__ W, ushort* __restrict__ Wt, int K, int N) {
  wprep_body(W, Wt, K, N);
}

// ---------------------------------------------------------------------------
// bf16 MFMA GEMM body: C[M][N] = A[M][K] @ Bt[N][K]^T, 128x128 tile, BK=64,
// 4 waves (2x2), each wave 64x64 = 4x4 tiles of 16x16x32 mfma.
// Staging via global_load_lds; swizzle per rule #21 (linear LDS dest,
// pre-swizzled global source col, matching read-side XOR).
// Optional vt_out: write C transposed per-head ([b*h][d][m]) instead of
// row-major — fuses the old vtr kernel into the V-projection epilogue.
// ---------------------------------------------------------------------------
template <bool F32_RES_OUT>
static __device__ __forceinline__ void gemm_body(
    const ushort* __restrict__ A, const ushort* __restrict__ Bt,
    const float* __restrict__ bias, const float* __restrict__ res,
    void* __restrict__ Cout, ushort* __restrict__ vt_out,
    int M, int N, int K, float scale, int m0, int n0) {
  __shared__ ushort As[128 * 64];   // linear, 16 KiB
  __shared__ ushort Bs[128 * 64];
  const int t = threadIdx.x;
  const int l = t & 63, w = t >> 6;
  const int lq = l & 15, lg = l >> 4;
  const int wr = w >> 1, wc = w & 1;
  f32x4 acc[4][4];
  #pragma unroll
  for (int mt = 0; mt < 4; ++mt)
    #pragma unroll
    for (int nt = 0; nt < 4; ++nt)
      #pragma unroll
      for (int e = 0; e < 4; ++e) acc[mt][nt][e] = 0.f;
  // staging geometry: chunk C = i*256 + w*64 + l covers row C>>3 (= i*32 +
  // w*8 + (l>>3)), source col pre-swizzled ((l&7)^(row&7))*8; row&7 == l>>3.
  const int srow = w * 8 + (l >> 3);
  const int scol = ((l & 7) ^ (l >> 3)) * 8;
  const ushort* pA = A + (size_t)(m0 + srow) * K + scol;
  const ushort* pB = Bt + (size_t)(n0 + srow) * K + scol;
  const int dbase = w * 512;               // shorts (wave chunk base)
  for (int k0 = 0; k0 < K; k0 += 64) {
    if (k0) __syncthreads();               // prior reads done before overwrite
    #pragma unroll
    for (int i = 0; i < 4; ++i) {
      gload16(pA + (size_t)(i * 32) * K + k0, &As[i * 2048 + dbase]);
      gload16(pB + (size_t)(i * 32) * K + k0, &Bs[i * 2048 + dbase]);
    }
    __syncthreads();                       // drains vmcnt -> tile visible
    #pragma unroll
    for (int ks = 0; ks < 2; ++ks) {
      bf16x8 af[4], bfr[4];
      #pragma unroll
      for (int mt = 0; mt < 4; ++mt) {
        const int R = wr * 64 + mt * 16 + lq;
        af[mt] = *(const bf16x8*)(
            &As[R * 64 + ((ks * 32 + lg * 8) ^ ((R & 7) * 8))]);
      }
      #pragma unroll
      for (int nt = 0; nt < 4; ++nt) {
        const int R = wc * 64 + nt * 16 + lq;
        bfr[nt] = *(const bf16x8*)(
            &Bs[R * 64 + ((ks * 32 + lg * 8) ^ ((R & 7) * 8))]);
      }
      #pragma unroll
      for (int mt = 0; mt < 4; ++mt)
        #pragma unroll
        for (int nt = 0; nt < 4; ++nt)
          acc[mt][nt] = __builtin_amdgcn_mfma_f32_16x16x32_bf16(
              af[mt], bfr[nt], acc[mt][nt], 0, 0, 0);
    }
  }
  #pragma unroll
  for (int nt = 0; nt < 4; ++nt) {
    const int colc = n0 + wc * 64 + nt * 16 + lq;
    const float bcol = bias ? bias[colc] : 0.f;
    #pragma unroll
    for (int mt = 0; mt < 4; ++mt) {
      #pragma unroll
      for (int i = 0; i < 4; ++i) {
        const size_t row = (size_t)(m0 + wr * 64 + mt * 16 + lg * 4 + i);
        float v = acc[mt][nt][i] * scale + bcol;
        if (vt_out) {
          // transposed per-head: vt[(bi*8+h)*64 + d][m], h=colc>>6, d=colc&63
          vt_out[(size_t)((((row >> 10) * 8 + (colc >> 6)) << 6) + (colc & 63)) * MCTX
                 + (row & (MCTX - 1))] = f2bf(v);
        } else if (F32_RES_OUT) {
          ((float*)Cout)[row * N + colc] = v + res[row * N + colc];
        } else {
          ((ushort*)Cout)[row * N + colc] = f2bf(v);
        }
      }
    }
  }
}

template <bool F32_RES_OUT>
__global__ __launch_bounds__(256) void mfma_gemm(
    const ushort* __restrict__ A, const ushort* __restrict__ Bt,
    const float* __restrict__ bias, const float* __restrict__ res,
    void* __restrict__ Cout, int M, int N, int K, float scale) {
  gemm_body<F32_RES_OUT>(A, Bt, bias, res, Cout, nullptr, M, N, K, scale,
                         blockIdx.y * 128, blockIdx.x * 128);
}

// K and V projection GEMMs in one launch (shared A = ynbf). V half writes
// the transposed per-head layout directly (old vtr kernel fused away).
__global__ __launch_bounds__(256) void mfma_gemm_kv(
    const ushort* __restrict__ A, const ushort* __restrict__ BtK,
    const ushort* __restrict__ BtV, const float* __restrict__ bv,
    ushort* __restrict__ Ck, ushort* __restrict__ vt_out) {
  const bool isV = blockIdx.x >= 4;
  gemm_body<false>(A, isV ? BtV : BtK, isV ? bv : nullptr, nullptr,
                   (void*)Ck, isV ? vt_out : nullptr, 4096, 512, 256, 1.f,
                   blockIdx.y * 128, (blockIdx.x & 3) * 128);
}

// ---------------------------------------------------------------------------
// Flash attention, bf16 MFMA — r4 structure + r7 phase stagger + ZERO-LDS P:
// PV uses v_mfma_f32_16x16x16_bf16, whose A-operand layout (lane holds
// A[row=l&15][k=lg*4+r]) IS the QK^T C-layout (key=16j+4lg+e). So P fragments
// are lane-local bf16x4 packs of sc[j][0..3] — the entire Ps LDS buffer, its
// write/read traffic (~35% of LDS volume) and the write->read lgkm latency
// are deleted. V fragments become b64 reads (same bytes, swizzle-compatible:
// XOR flips short-index bits >=3, b64 reads are 4-short aligned).
// q pre-scaled 0.125*log2e; swapped QK^T; exp2-domain tree softmax; K/V LDS
// double-buffered (one barrier/tile); reg prefetch at loop top; XCD swizzle;
// phase stagger tile0=(bid&3)*4; defer-max THR=8; K/V tiles XOR-swizzled.
// NOTE: needs ~128 VGPR; do NOT raise min-waves past 4/EU (r3: spill).
// Do NOT shrink to 4-wave blocks or single-buffer (r5: 68.8 us regression).
// ---------------------------------------------------------------------------
__global__ __launch_bounds__(512, 4) void attn_mfma(
    const ushort* __restrict__ q, const ushort* __restrict__ k,
    const ushort* __restrict__ vt, ushort* __restrict__ ao) {
  // XCD-aware swizzle (bijective: 512 = 8 * 64)
  const int bid = blockIdx.x + 16 * (blockIdx.y + 8 * blockIdx.z);
  const int swz = (bid & 7) * 64 + (bid >> 3);
  const int bi = swz >> 7;
  const int h = (swz >> 4) & 7;
  const int n0 = (swz & 15) * 256;
  const int tile0 = (bid & 3) << 2;        // phase stagger: 0,4,8,12
  __shared__ ushort Ks[2][64 * 64];
  __shared__ ushort Vs[2][64 * 64];
  const int t = threadIdx.x;
  const int l = t & 63, w = t >> 6;
  const int lq = l & 15, lg = l >> 4;

  // Q fragments (B operand: col=q-row-in-tile, k=d) direct from global.
  bf16x8 bq[2][2];
  #pragma unroll
  for (int g = 0; g < 2; ++g) {
    const size_t qrow = (size_t)(bi * HW + n0 + w * 32 + g * 16 + lq);
    #pragma unroll
    for (int ks = 0; ks < 2; ++ks)
      bq[g][ks] = *(const bf16x8*)(q + qrow * INNER + h * DHEAD + ks * 32 + lg * 8);
  }

  float m_run[2] = {-1e30f, -1e30f}, l_run[2] = {0.f, 0.f};
  f32x4 oacc[2][4];
  #pragma unroll
  for (int g = 0; g < 2; ++g)
    #pragma unroll
    for (int dt = 0; dt < 4; ++dt)
      #pragma unroll
      for (int e = 0; e < 4; ++e) oacc[g][dt][e] = 0.f;

  // staging: 64x64 bf16 tile = 512 uint4; 512 threads -> 1 uint4 each per tile
  const int rr = t >> 3, cc = (t & 7) * 8;
  const ushort* kptr = k + (size_t)(bi * MCTX + rr) * INNER + h * DHEAD + cc;
  const ushort* vptr = vt + (size_t)((bi * HEADS + h) * 64 + rr) * MCTX + cc;
  const int sidx = (rr * 64 + cc) ^ ((rr & 7) << 3);

  {  // stage first tile (tile0) into buffer 0
    const int ms = tile0 << 6;
    uint4 k0v = *(const uint4*)(kptr + (size_t)ms * INNER);
    uint4 v0v = *(const uint4*)(vptr + ms);
    *(uint4*)(&Ks[0][sidx]) = k0v;
    *(uint4*)(&Vs[0][sidx]) = v0v;
  }
  __syncthreads();

  // softmax for one q-group: scores -> P (lane-local bf16x4 frags), online
  // max/sum with tree reductions. No LDS.
  auto softmax_group = [&](f32x4 (&scg)[4], float& mr, float& lr,
                           f32x4 (&oa)[4], bf16x4 (&paf)[4]) {
    f32x4 mv;
    #pragma unroll
    for (int e = 0; e < 4; ++e)
      mv[e] = fmaxf(fmaxf(scg[0][e], scg[1][e]), fmaxf(scg[2][e], scg[3][e]));
    float mloc = fmaxf(fmaxf(mv[0], mv[1]), fmaxf(mv[2], mv[3]));
    mloc = fmaxf(mloc, __shfl_xor(mloc, 16));
    mloc = fmaxf(mloc, __shfl_xor(mloc, 32));
    // defer-max: only rescale when some q-row's max grew by > 8 (log2 units)
    if (!__all((int)(mloc - mr <= 8.f))) {
      const float mnew = fmaxf(mr, mloc);
      const float corr = __builtin_amdgcn_exp2f(mr - mnew);
      lr *= corr;
      mr = mnew;
      #pragma unroll
      for (int i = 0; i < 4; ++i) {
        float ci = __shfl(corr, lg * 4 + i);
        #pragma unroll
        for (int dt = 0; dt < 4; ++dt) oa[dt][i] *= ci;
      }
    }
    #pragma unroll
    for (int j = 0; j < 4; ++j)
      #pragma unroll
      for (int e = 0; e < 4; ++e)
        scg[j][e] = __builtin_amdgcn_exp2f(scg[j][e] - mr);
    f32x4 s4;
    #pragma unroll
    for (int e = 0; e < 4; ++e)
      s4[e] = (scg[0][e] + scg[1][e]) + (scg[2][e] + scg[3][e]);
    float psum = (s4[0] + s4[1]) + (s4[2] + s4[3]);
    psum += __shfl_xor(psum, 16);
    psum += __shfl_xor(psum, 32);
    lr += psum;
    // pack P[q=lq][key=16j+4lg+e] -> bf16x4 (the 16x16x16 A-frag, lane-local)
    #pragma unroll
    for (int j = 0; j < 4; ++j) {
      uint2 pk;
      pk.x = (uint)f2bf(scg[j][0]) | ((uint)f2bf(scg[j][1]) << 16);
      pk.y = (uint)f2bf(scg[j][2]) | ((uint)f2bf(scg[j][3]) << 16);
      paf[j] = *reinterpret_cast<bf16x4*>(&pk);
    }
  };

  #pragma unroll 2
  for (int it = 0; it < 16; ++it) {
    const int buf = it & 1;
    const bool more = (it + 1) < 16;
    const int mnext = ((tile0 + it + 1) & 15) << 6;
    uint4 kpre{}, vpre{};
    if (more) {  // prefetch next tile; consumed mid-iteration, after sm(g0)
      kpre = *(const uint4*)(kptr + (size_t)mnext * INNER);
      vpre = *(const uint4*)(vptr + mnext);
    }
    // scores both groups: St[key][q], ak shared across groups
    f32x4 sc[2][4];
    #pragma unroll
    for (int g = 0; g < 2; ++g)
      #pragma unroll
      for (int j = 0; j < 4; ++j)
        #pragma unroll
        for (int e = 0; e < 4; ++e) sc[g][j][e] = 0.f;
    __builtin_amdgcn_s_setprio(1);
    #pragma unroll
    for (int j = 0; j < 4; ++j) {
      #pragma unroll
      for (int ks = 0; ks < 2; ++ks) {
        const int krow = j * 16 + lq;
        bf16x8 ak = *(const bf16x8*)(
            &Ks[buf][(krow * 64 + ks * 32 + lg * 8) ^ ((krow & 7) << 3)]);
        sc[0][j] = __builtin_amdgcn_mfma_f32_16x16x32_bf16(ak, bq[0][ks], sc[0][j], 0, 0, 0);
        sc[1][j] = __builtin_amdgcn_mfma_f32_16x16x32_bf16(ak, bq[1][ks], sc[1][j], 0, 0, 0);
      }
    }
    __builtin_amdgcn_s_setprio(0);
    bf16x4 pa0[4], pa1[4];
    // group 0 softmax (P stays in registers)
    softmax_group(sc[0], m_run[0], l_run[0], oacc[0], pa0);
    // stage next tile into the other buffer (safe: buf^1 last read before
    // the previous barrier); drains during sm(g1) + PV
    if (more) {
      *(uint4*)(&Ks[buf ^ 1][sidx]) = kpre;
      *(uint4*)(&Vs[buf ^ 1][sidx]) = vpre;
    }
    // group 1 softmax
    softmax_group(sc[1], m_run[1], l_run[1], oacc[1], pa1);
    // PV both groups via 16x16x16 MFMA: O[q][d] += P @ V.
    // B-frag: V[key=16j+4lg+r][d=dt*16+lq] = Vs[dt*16+lq][16j+4lg .. +3] (b64)
    __builtin_amdgcn_s_setprio(1);
    #pragma unroll
    for (int dt = 0; dt < 4; ++dt) {
      const int vrow = dt * 16 + lq;
      #pragma unroll
      for (int j = 0; j < 4; ++j) {
        bf16x4 vb = *(const bf16x4*)(
            &Vs[buf][(vrow * 64 + j * 16 + lg * 4) ^ ((vrow & 7) << 3)]);
        oacc[0][dt] = mfma16(pa0[j], vb, oacc[0][dt]);
        oacc[1][dt] = mfma16(pa1[j], vb, oacc[1][dt]);
      }
    }
    __builtin_amdgcn_s_setprio(0);
    __syncthreads();
  }
  #pragma unroll
  for (int g = 0; g < 2; ++g) {
    const float rl = 1.f / l_run[g];
    #pragma unroll
    for (int i = 0; i < 4; ++i) {
      float li = __shfl(rl, lg * 4 + i);
      const size_t row = (size_t)(bi * HW + n0 + w * 32 + g * 16 + lg * 4 + i);
      #pragma unroll
      for (int dt = 0; dt < 4; ++dt)
        ao[row * INNER + h * DHEAD + dt * 16 + lq] = f2bf(oacc[g][dt][i] * li);
    }
  }
}

// ---------------------------------------------------------------------------
extern "C" void kernel_launch(void* const* d_in, const int* in_sizes, int n_in,
                              void* d_out, int out_size, void* d_ws, size_t ws_size,
                              hipStream_t stream) {
  const float* x     = (const float*)d_in[0];
  const float* y     = (const float*)d_in[1];
  const float* ln_xg = (const float*)d_in[2];
  const float* ln_xb = (const float*)d_in[3];
  const float* ln_yg = (const float*)d_in[4];
  const float* ln_yb = (const float*)d_in[5];
  const float* Wq    = (const float*)d_in[6];
  const float* Wk    = (const float*)d_in[7];
  const float* Wv    = (const float*)d_in[8];
  const float* bv    = (const float*)d_in[9];
  const float* Wo    = (const float*)d_in[10];
  const float* bo    = (const float*)d_in[11];
  float* out = (float*)d_out;

  char* p = (char*)d_ws;
  float*  xn   = (float*)p;  p += (size_t)16384 * 256 * 4;
  ushort* xnbf = (ushort*)p; p += (size_t)16384 * 256 * 2;
  ushort* ynbf = (ushort*)p; p += (size_t)4096 * 256 * 2;
  ushort* wtq  = (ushort*)p; p += (size_t)512 * 256 * 2;
  ushort* wtk  = (ushort*)p; p += (size_t)512 * 256 * 2;
  ushort* wtv  = (ushort*)p; p += (size_t)512 * 256 * 2;
  ushort* wto  = (ushort*)p; p += (size_t)256 * 512 * 2;
  ushort* qbf  = (ushort*)p; p += (size_t)16384 * 512 * 2;
  ushort* kbf  = (ushort*)p; p += (size_t)4096 * 512 * 2;
  ushort* vtb  = (ushort*)p; p += (size_t)4096 * 512 * 2;
  ushort* aobf = (ushort*)p; p += (size_t)16384 * 512 * 2;

  wprep3_kernel<<<dim3(8, 4, 3), 256, 0, stream>>>(Wq, Wk, Wv, wtq, wtk, wtv);
  wprep_kernel<<<dim3(4, 8), 256, 0, stream>>>(Wo, wto, 512, 256);
  ln_x_kernel<<<dim3(BATCH * (HW / 32)), 256, 0, stream>>>(x, ln_xg, ln_xb, xn, xnbf);
  ln_y_kernel<<<dim3(BATCH * MCTX / 4), 256, 0, stream>>>(y, ln_yg, ln_yb, ynbf);
  // q = (xn @ Wq) * 0.125 * log2(e)  (scale folded; softmax runs in exp2 domain)
  mfma_gemm<false><<<dim3(4, 128), 256, 0, stream>>>(
      xnbf, wtq, nullptr, nullptr, qbf, 16384, 512, 256, 0.1803368801111204f);
  // K + V projections; V written directly in transposed per-head layout
  mfma_gemm_kv<<<dim3(8, 32), 256, 0, stream>>>(ynbf, wtk, wtv, bv, kbf, vtb);
  attn_mfma<<<dim3(HW / 256, HEADS, BATCH), 512, 0, stream>>>(qbf, kbf, vtb, aobf);
  // out = ao @ Wo + bo + xn
  mfma_gemm<true><<<dim3(2, 128), 256, 0, stream>>>(
      aobf, wto, bo, xn, out, 16384, 256, 512, 1.f);
}

// Round 9
// 113.938 us; speedup vs baseline: 1.0464x; 1.0464x over previous
//
#include <hip/hip_runtime.h>
#include <hip/hip_bf16.h>
#include <cstddef>
#include <cstdint>

#define BATCH 4
#define CDIM 256
#define HW 4096
#define MCTX 1024
#define CTX 256
#define HEADS 8
#define DHEAD 64
#define INNER 512

typedef __attribute__((ext_vector_type(8))) short bf16x8;
typedef __attribute__((ext_vector_type(4))) float f32x4;

static __device__ __forceinline__ ushort f2bf(float f) {
  __hip_bfloat16 h = __float2bfloat16(f);
  return *reinterpret_cast<ushort*>(&h);
}

// async global->LDS, 16B per lane. LDS dest is wave-uniform base + lane*16.
static __device__ __forceinline__ void gload16(const void* g, void* l) {
  __builtin_amdgcn_global_load_lds(
      (const __attribute__((address_space(1))) void*)(uintptr_t)g,
      (__attribute__((address_space(3))) void*)(uint32_t)(uintptr_t)l,
      16, 0, 0);
}

// ---------------------------------------------------------------------------
// LN over channels of x with layout transpose. x:[b,256,4096] -> xn:[b,4096,256]
// Load phase vectorized: float4 per lane along n (G13).
// ---------------------------------------------------------------------------
__global__ __launch_bounds__(256) void ln_x_kernel(
    const float* __restrict__ x, const float* __restrict__ g,
    const float* __restrict__ bta, float* __restrict__ xn,
    ushort* __restrict__ xnbf) {
  const int blk = blockIdx.x;
  const int bi = blk / (HW / 32);
  const int n0 = (blk % (HW / 32)) * 32;
  __shared__ float xt[32][257];
  __shared__ float smu[32], srs[32];
  const int t = threadIdx.x;
  const float* xb = x + (size_t)bi * CDIM * HW;
  {
    const int cr = t >> 3;            // c within pass (32 per pass)
    const int n4 = (t & 7) * 4;       // 8 lanes x float4 cover 32 n
    #pragma unroll
    for (int pass = 0; pass < 8; ++pass) {
      const int c = pass * 32 + cr;
      float4 v = *(const float4*)(xb + (size_t)c * HW + n0 + n4);
      xt[n4 + 0][c] = v.x; xt[n4 + 1][c] = v.y;
      xt[n4 + 2][c] = v.z; xt[n4 + 3][c] = v.w;
    }
  }
  __syncthreads();
  const int col = t >> 3, j = t & 7;
  float s = 0.f, ss = 0.f;
  #pragma unroll
  for (int c = j; c < CDIM; c += 8) {
    float v = xt[col][c];
    s += v; ss += v * v;
  }
  #pragma unroll
  for (int off = 1; off < 8; off <<= 1) {
    s += __shfl_xor(s, off);
    ss += __shfl_xor(ss, off);
  }
  if (j == 0) {
    float mu = s * (1.f / CDIM);
    smu[col] = mu;
    srs[col] = rsqrtf(ss * (1.f / CDIM) - mu * mu + 1e-5f);
  }
  __syncthreads();
  const float gv = g[t], bvv = bta[t];
  float* xnb = xn + ((size_t)bi * HW + n0) * CDIM;
  ushort* xbb = xnbf + ((size_t)bi * HW + n0) * CDIM;
  #pragma unroll 4
  for (int n = 0; n < 32; ++n) {
    float val = (xt[n][t] - smu[n]) * srs[n] * gv + bvv;
    xnb[(size_t)n * CDIM + t] = val;
    xbb[(size_t)n * CDIM + t] = f2bf(val);
  }
}

// ---------------------------------------------------------------------------
// LN y rows -> bf16. 4 waves per block, one row each.
// ---------------------------------------------------------------------------
__global__ __launch_bounds__(256) void ln_y_kernel(
    const float* __restrict__ y, const float* __restrict__ g,
    const float* __restrict__ bta, ushort* __restrict__ ynbf) {
  const int row = blockIdx.x * 4 + (threadIdx.x >> 6);
  const int t = threadIdx.x & 63;
  float4 v = ((const float4*)(y + (size_t)row * CTX))[t];
  float s = v.x + v.y + v.z + v.w;
  float ss = v.x * v.x + v.y * v.y + v.z * v.z + v.w * v.w;
  #pragma unroll
  for (int off = 1; off < 64; off <<= 1) {
    s += __shfl_xor(s, off);
    ss += __shfl_xor(ss, off);
  }
  float mu = s * (1.f / CTX);
  float rs = rsqrtf(ss * (1.f / CTX) - mu * mu + 1e-5f);
  float4 gv = ((const float4*)g)[t];
  float4 b4 = ((const float4*)bta)[t];
  ushort4 ob;
  ob.x = f2bf((v.x - mu) * rs * gv.x + b4.x);
  ob.y = f2bf((v.y - mu) * rs * gv.y + b4.y);
  ob.z = f2bf((v.z - mu) * rs * gv.z + b4.z);
  ob.w = f2bf((v.w - mu) * rs * gv.w + b4.w);
  *(ushort4*)(ynbf + (size_t)row * CTX + t * 4) = ob;
}

// ---------------------------------------------------------------------------
// Weight prep: W [K][N] fp32 -> Wt [N][K] bf16 (64x64 LDS transpose tiles).
// wprep4: ALL FOUR weights in ONE launch. z<3: Wq/Wk/Wv (256x512, grid 8x4).
// z==3: Wo (512x256) — bijective remap (x,y)->(x&3, y*2+(x>>2)) gives 4x8.
// ---------------------------------------------------------------------------
static __device__ __forceinline__ void wprep_body(
    const float* __restrict__ W, ushort* __restrict__ Wt, int K, int N,
    int bx, int by) {
  __shared__ ushort T[64][65];
  const int k0 = by * 64, n0 = bx * 64;
  const int t = threadIdx.x;
  #pragma unroll
  for (int rr = 0; rr < 4; ++rr) {
    int row = rr * 16 + (t >> 4);          // k
    int c = (t & 15) * 4;                  // n
    float4 wv = *(const float4*)(W + (size_t)(k0 + row) * N + n0 + c);
    T[row][c + 0] = f2bf(wv.x); T[row][c + 1] = f2bf(wv.y);
    T[row][c + 2] = f2bf(wv.z); T[row][c + 3] = f2bf(wv.w);
  }
  __syncthreads();
  #pragma unroll
  for (int rr = 0; rr < 4; ++rr) {
    int nrow = rr * 16 + (t >> 4);
    int kc = (t & 15) * 4;
    ushort4 o;
    o.x = T[kc + 0][nrow]; o.y = T[kc + 1][nrow];
    o.z = T[kc + 2][nrow]; o.w = T[kc + 3][nrow];
    *(ushort4*)(Wt + (size_t)(n0 + nrow) * K + k0 + kc) = o;
  }
}

__global__ __launch_bounds__(256) void wprep4_kernel(
    const float* __restrict__ W0, const float* __restrict__ W1,
    const float* __restrict__ W2, const float* __restrict__ W3,
    ushort* __restrict__ T0, ushort* __restrict__ T1,
    ushort* __restrict__ T2, ushort* __restrict__ T3) {
  const int z = blockIdx.z;
  if (z < 3) {
    const float* W = (z == 0) ? W0 : (z == 1) ? W1 : W2;
    ushort* Wt = (z == 0) ? T0 : (z == 1) ? T1 : T2;
    wprep_body(W, Wt, 256, 512, blockIdx.x, blockIdx.y);
  } else {
    wprep_body(W3, T3, 512, 256, blockIdx.x & 3,
               blockIdx.y * 2 + (blockIdx.x >> 2));
  }
}

// ---------------------------------------------------------------------------
// bf16 MFMA GEMM body: C[M][N] = A[M][K] @ Bt[N][K]^T, 128x128 tile, BK=64,
// 4 waves (2x2), each wave 64x64 = 4x4 tiles of 16x16x32 mfma.
// Staging via global_load_lds; swizzle per rule #21 (linear LDS dest,
// pre-swizzled global source col, matching read-side XOR).
// Optional vt_out: write C transposed per-head ([b*h][d][m]) instead of
// row-major — fuses the old vtr kernel into the V-projection epilogue.
// ---------------------------------------------------------------------------
template <bool F32_RES_OUT>
static __device__ __forceinline__ void gemm_body(
    const ushort* __restrict__ A, const ushort* __restrict__ Bt,
    const float* __restrict__ bias, const float* __restrict__ res,
    void* __restrict__ Cout, ushort* __restrict__ vt_out,
    int M, int N, int K, float scale, int m0, int n0) {
  __shared__ ushort As[128 * 64];   // linear, 16 KiB
  __shared__ ushort Bs[128 * 64];
  const int t = threadIdx.x;
  const int l = t & 63, w = t >> 6;
  const int lq = l & 15, lg = l >> 4;
  const int wr = w >> 1, wc = w & 1;
  f32x4 acc[4][4];
  #pragma unroll
  for (int mt = 0; mt < 4; ++mt)
    #pragma unroll
    for (int nt = 0; nt < 4; ++nt)
      #pragma unroll
      for (int e = 0; e < 4; ++e) acc[mt][nt][e] = 0.f;
  // staging geometry: chunk C = i*256 + w*64 + l covers row C>>3 (= i*32 +
  // w*8 + (l>>3)), source col pre-swizzled ((l&7)^(row&7))*8; row&7 == l>>3.
  const int srow = w * 8 + (l >> 3);
  const int scol = ((l & 7) ^ (l >> 3)) * 8;
  const ushort* pA = A + (size_t)(m0 + srow) * K + scol;
  const ushort* pB = Bt + (size_t)(n0 + srow) * K + scol;
  const int dbase = w * 512;               // shorts (wave chunk base)
  for (int k0 = 0; k0 < K; k0 += 64) {
    if (k0) __syncthreads();               // prior reads done before overwrite
    #pragma unroll
    for (int i = 0; i < 4; ++i) {
      gload16(pA + (size_t)(i * 32) * K + k0, &As[i * 2048 + dbase]);
      gload16(pB + (size_t)(i * 32) * K + k0, &Bs[i * 2048 + dbase]);
    }
    __syncthreads();                       // drains vmcnt -> tile visible
    #pragma unroll
    for (int ks = 0; ks < 2; ++ks) {
      bf16x8 af[4], bfr[4];
      #pragma unroll
      for (int mt = 0; mt < 4; ++mt) {
        const int R = wr * 64 + mt * 16 + lq;
        af[mt] = *(const bf16x8*)(
            &As[R * 64 + ((ks * 32 + lg * 8) ^ ((R & 7) * 8))]);
      }
      #pragma unroll
      for (int nt = 0; nt < 4; ++nt) {
        const int R = wc * 64 + nt * 16 + lq;
        bfr[nt] = *(const bf16x8*)(
            &Bs[R * 64 + ((ks * 32 + lg * 8) ^ ((R & 7) * 8))]);
      }
      #pragma unroll
      for (int mt = 0; mt < 4; ++mt)
        #pragma unroll
        for (int nt = 0; nt < 4; ++nt)
          acc[mt][nt] = __builtin_amdgcn_mfma_f32_16x16x32_bf16(
              af[mt], bfr[nt], acc[mt][nt], 0, 0, 0);
    }
  }
  #pragma unroll
  for (int nt = 0; nt < 4; ++nt) {
    const int colc = n0 + wc * 64 + nt * 16 + lq;
    const float bcol = bias ? bias[colc] : 0.f;
    #pragma unroll
    for (int mt = 0; mt < 4; ++mt) {
      #pragma unroll
      for (int i = 0; i < 4; ++i) {
        const size_t row = (size_t)(m0 + wr * 64 + mt * 16 + lg * 4 + i);
        float v = acc[mt][nt][i] * scale + bcol;
        if (vt_out) {
          // transposed per-head: vt[(bi*8+h)*64 + d][m], h=colc>>6, d=colc&63
          vt_out[(size_t)((((row >> 10) * 8 + (colc >> 6)) << 6) + (colc & 63)) * MCTX
                 + (row & (MCTX - 1))] = f2bf(v);
        } else if (F32_RES_OUT) {
          ((float*)Cout)[row * N + colc] = v + res[row * N + colc];
        } else {
          ((ushort*)Cout)[row * N + colc] = f2bf(v);
        }
      }
    }
  }
}

template <bool F32_RES_OUT>
__global__ __launch_bounds__(256) void mfma_gemm(
    const ushort* __restrict__ A, const ushort* __restrict__ Bt,
    const float* __restrict__ bias, const float* __restrict__ res,
    void* __restrict__ Cout, int M, int N, int K, float scale) {
  gemm_body<F32_RES_OUT>(A, Bt, bias, res, Cout, nullptr, M, N, K, scale,
                         blockIdx.y * 128, blockIdx.x * 128);
}

// K and V projection GEMMs in one launch (shared A = ynbf). V half writes
// the transposed per-head layout directly (old vtr kernel fused away).
__global__ __launch_bounds__(256) void mfma_gemm_kv(
    const ushort* __restrict__ A, const ushort* __restrict__ BtK,
    const ushort* __restrict__ BtV, const float* __restrict__ bv,
    ushort* __restrict__ Ck, ushort* __restrict__ vt_out) {
  const bool isV = blockIdx.x >= 4;
  gemm_body<false>(A, isV ? BtV : BtK, isV ? bv : nullptr, nullptr,
                   (void*)Ck, isV ? vt_out : nullptr, 4096, 512, 256, 1.f,
                   blockIdx.y * 128, (blockIdx.x & 3) * 128);
}

// ---------------------------------------------------------------------------
// Flash attention, bf16 MFMA — r7 structure, the measured optimum (61.8 us).
// q pre-scaled 0.125*log2e; swapped QK^T; exp2-domain tree softmax; K/V LDS
// double-buffered (one barrier/tile); reg prefetch at loop top; stage between
// sm0 and sm1; P via per-wave Ps LDS (write->sm1->read hides the round-trip);
// PV at K=32 (16x16x32). XCD swizzle; phase stagger tile0=(bid&3)*4;
// defer-max THR=8; tiles XOR-swizzled: short_idx ^= (row&7)<<3.
// LEDGER (do not revisit): 4-wave blocks -13% (r5); gload_lds+shared-Ps -13%
// (r5); min-waves>4 spills catastrophically (r3); zero-LDS-P via K=16 PV -7%
// (r8: doubles MFMA issue + V ds_read count); intra-tile reorder flat (r4).
// ---------------------------------------------------------------------------
__global__ __launch_bounds__(512, 4) void attn_mfma(
    const ushort* __restrict__ q, const ushort* __restrict__ k,
    const ushort* __restrict__ vt, ushort* __restrict__ ao) {
  // XCD-aware swizzle (bijective: 512 = 8 * 64)
  const int bid = blockIdx.x + 16 * (blockIdx.y + 8 * blockIdx.z);
  const int swz = (bid & 7) * 64 + (bid >> 3);
  const int bi = swz >> 7;
  const int h = (swz >> 4) & 7;
  const int n0 = (swz & 15) * 256;
  const int tile0 = (bid & 3) << 2;        // phase stagger: 0,4,8,12
  __shared__ ushort Ks[2][64 * 64];
  __shared__ ushort Vs[2][64 * 64];
  __shared__ ushort Ps[8][2][16 * 64];
  const int t = threadIdx.x;
  const int l = t & 63, w = t >> 6;
  const int lq = l & 15, lg = l >> 4;

  // Q fragments (B operand: col=q-row-in-tile, k=d) direct from global.
  bf16x8 bq[2][2];
  #pragma unroll
  for (int g = 0; g < 2; ++g) {
    const size_t qrow = (size_t)(bi * HW + n0 + w * 32 + g * 16 + lq);
    #pragma unroll
    for (int ks = 0; ks < 2; ++ks)
      bq[g][ks] = *(const bf16x8*)(q + qrow * INNER + h * DHEAD + ks * 32 + lg * 8);
  }

  float m_run[2] = {-1e30f, -1e30f}, l_run[2] = {0.f, 0.f};
  f32x4 oacc[2][4];
  #pragma unroll
  for (int g = 0; g < 2; ++g)
    #pragma unroll
    for (int dt = 0; dt < 4; ++dt)
      #pragma unroll
      for (int e = 0; e < 4; ++e) oacc[g][dt][e] = 0.f;

  // staging: 64x64 bf16 tile = 512 uint4; 512 threads -> 1 uint4 each per tile
  const int rr = t >> 3, cc = (t & 7) * 8;
  const ushort* kptr = k + (size_t)(bi * MCTX + rr) * INNER + h * DHEAD + cc;
  const ushort* vptr = vt + (size_t)((bi * HEADS + h) * 64 + rr) * MCTX + cc;
  const int sidx = (rr * 64 + cc) ^ ((rr & 7) << 3);

  {  // stage first tile (tile0) into buffer 0
    const int ms = tile0 << 6;
    uint4 k0v = *(const uint4*)(kptr + (size_t)ms * INNER);
    uint4 v0v = *(const uint4*)(vptr + ms);
    *(uint4*)(&Ks[0][sidx]) = k0v;
    *(uint4*)(&Vs[0][sidx]) = v0v;
  }
  __syncthreads();

  // softmax for one q-group: scores -> P, online max/sum, tree reductions.
  auto softmax_group = [&](f32x4 (&scg)[4], float& mr, float& lr,
                           f32x4 (&oa)[4], ushort* psw) {
    f32x4 mv;
    #pragma unroll
    for (int e = 0; e < 4; ++e)
      mv[e] = fmaxf(fmaxf(scg[0][e], scg[1][e]), fmaxf(scg[2][e], scg[3][e]));
    float mloc = fmaxf(fmaxf(mv[0], mv[1]), fmaxf(mv[2], mv[3]));
    mloc = fmaxf(mloc, __shfl_xor(mloc, 16));
    mloc = fmaxf(mloc, __shfl_xor(mloc, 32));
    // defer-max: only rescale when some q-row's max grew by > 8 (log2 units)
    if (!__all((int)(mloc - mr <= 8.f))) {
      const float mnew = fmaxf(mr, mloc);
      const float corr = __builtin_amdgcn_exp2f(mr - mnew);
      lr *= corr;
      mr = mnew;
      #pragma unroll
      for (int i = 0; i < 4; ++i) {
        float ci = __shfl(corr, lg * 4 + i);
        #pragma unroll
        for (int dt = 0; dt < 4; ++dt) oa[dt][i] *= ci;
      }
    }
    #pragma unroll
    for (int j = 0; j < 4; ++j)
      #pragma unroll
      for (int e = 0; e < 4; ++e)
        scg[j][e] = __builtin_amdgcn_exp2f(scg[j][e] - mr);
    f32x4 s4;
    #pragma unroll
    for (int e = 0; e < 4; ++e)
      s4[e] = (scg[0][e] + scg[1][e]) + (scg[2][e] + scg[3][e]);
    float psum = (s4[0] + s4[1]) + (s4[2] + s4[3]);
    psum += __shfl_xor(psum, 16);
    psum += __shfl_xor(psum, 32);
    lr += psum;
    // write P[q=lq][key] (bf16, swizzled) — per-wave region, no barrier
    #pragma unroll
    for (int j = 0; j < 4; ++j) {
      uint2 pk;
      pk.x = (uint)f2bf(scg[j][0]) | ((uint)f2bf(scg[j][1]) << 16);
      pk.y = (uint)f2bf(scg[j][2]) | ((uint)f2bf(scg[j][3]) << 16);
      *(uint2*)(psw + ((lq * 64 + j * 16 + lg * 4) ^ ((lq & 7) << 3))) = pk;
    }
  };

  #pragma unroll 2
  for (int it = 0; it < 16; ++it) {
    const int buf = it & 1;
    const bool more = (it + 1) < 16;
    const int mnext = ((tile0 + it + 1) & 15) << 6;
    uint4 kpre{}, vpre{};
    if (more) {  // prefetch next tile; consumed mid-iteration, after sm(g0)
      kpre = *(const uint4*)(kptr + (size_t)mnext * INNER);
      vpre = *(const uint4*)(vptr + mnext);
    }
    // scores both groups: St[key][q], ak shared across groups
    f32x4 sc[2][4];
    #pragma unroll
    for (int g = 0; g < 2; ++g)
      #pragma unroll
      for (int j = 0; j < 4; ++j)
        #pragma unroll
        for (int e = 0; e < 4; ++e) sc[g][j][e] = 0.f;
    __builtin_amdgcn_s_setprio(1);
    #pragma unroll
    for (int j = 0; j < 4; ++j) {
      #pragma unroll
      for (int ks = 0; ks < 2; ++ks) {
        const int krow = j * 16 + lq;
        bf16x8 ak = *(const bf16x8*)(
            &Ks[buf][(krow * 64 + ks * 32 + lg * 8) ^ ((krow & 7) << 3)]);
        sc[0][j] = __builtin_amdgcn_mfma_f32_16x16x32_bf16(ak, bq[0][ks], sc[0][j], 0, 0, 0);
        sc[1][j] = __builtin_amdgcn_mfma_f32_16x16x32_bf16(ak, bq[1][ks], sc[1][j], 0, 0, 0);
      }
    }
    __builtin_amdgcn_s_setprio(0);
    // group 0 softmax + P write
    softmax_group(sc[0], m_run[0], l_run[0], oacc[0], &Ps[w][0][0]);
    // stage next tile into the other buffer (safe: buf^1 last read before
    // the previous barrier); drains during sm(g1) + PV
    if (more) {
      *(uint4*)(&Ks[buf ^ 1][sidx]) = kpre;
      *(uint4*)(&Vs[buf ^ 1][sidx]) = vpre;
    }
    // group 1 softmax + P write (hides group-0 Ps write->read latency)
    softmax_group(sc[1], m_run[1], l_run[1], oacc[1], &Ps[w][1][0]);
    // read P fragments for both groups
    bf16x8 pa[2][2];
    #pragma unroll
    for (int g = 0; g < 2; ++g)
      #pragma unroll
      for (int ks = 0; ks < 2; ++ks)
        pa[g][ks] = *(const bf16x8*)(
            &Ps[w][g][(lq * 64 + ks * 32 + lg * 8) ^ ((lq & 7) << 3)]);
    // PV both groups: O[q][d] += P @ V; vb shared across groups
    __builtin_amdgcn_s_setprio(1);
    #pragma unroll
    for (int dt = 0; dt < 4; ++dt) {
      #pragma unroll
      for (int ks = 0; ks < 2; ++ks) {
        const int vrow = dt * 16 + lq;
        bf16x8 vb = *(const bf16x8*)(
            &Vs[buf][(vrow * 64 + ks * 32 + lg * 8) ^ ((vrow & 7) << 3)]);
        oacc[0][dt] = __builtin_amdgcn_mfma_f32_16x16x32_bf16(pa[0][ks], vb, oacc[0][dt], 0, 0, 0);
        oacc[1][dt] = __builtin_amdgcn_mfma_f32_16x16x32_bf16(pa[1][ks], vb, oacc[1][dt], 0, 0, 0);
      }
    }
    __builtin_amdgcn_s_setprio(0);
    __syncthreads();
  }
  #pragma unroll
  for (int g = 0; g < 2; ++g) {
    const float rl = 1.f / l_run[g];
    #pragma unroll
    for (int i = 0; i < 4; ++i) {
      float li = __shfl(rl, lg * 4 + i);
      const size_t row = (size_t)(bi * HW + n0 + w * 32 + g * 16 + lg * 4 + i);
      #pragma unroll
      for (int dt = 0; dt < 4; ++dt)
        ao[row * INNER + h * DHEAD + dt * 16 + lq] = f2bf(oacc[g][dt][i] * li);
    }
  }
}

// ---------------------------------------------------------------------------
extern "C" void kernel_launch(void* const* d_in, const int* in_sizes, int n_in,
                              void* d_out, int out_size, void* d_ws, size_t ws_size,
                              hipStream_t stream) {
  const float* x     = (const float*)d_in[0];
  const float* y     = (const float*)d_in[1];
  const float* ln_xg = (const float*)d_in[2];
  const float* ln_xb = (const float*)d_in[3];
  const float* ln_yg = (const float*)d_in[4];
  const float* ln_yb = (const float*)d_in[5];
  const float* Wq    = (const float*)d_in[6];
  const float* Wk    = (const float*)d_in[7];
  const float* Wv    = (const float*)d_in[8];
  const float* bv    = (const float*)d_in[9];
  const float* Wo    = (const float*)d_in[10];
  const float* bo    = (const float*)d_in[11];
  float* out = (float*)d_out;

  char* p = (char*)d_ws;
  float*  xn   = (float*)p;  p += (size_t)16384 * 256 * 4;
  ushort* xnbf = (ushort*)p; p += (size_t)16384 * 256 * 2;
  ushort* ynbf = (ushort*)p; p += (size_t)4096 * 256 * 2;
  ushort* wtq  = (ushort*)p; p += (size_t)512 * 256 * 2;
  ushort* wtk  = (ushort*)p; p += (size_t)512 * 256 * 2;
  ushort* wtv  = (ushort*)p; p += (size_t)512 * 256 * 2;
  ushort* wto  = (ushort*)p; p += (size_t)256 * 512 * 2;
  ushort* qbf  = (ushort*)p; p += (size_t)16384 * 512 * 2;
  ushort* kbf  = (ushort*)p; p += (size_t)4096 * 512 * 2;
  ushort* vtb  = (ushort*)p; p += (size_t)4096 * 512 * 2;
  ushort* aobf = (ushort*)p; p += (size_t)16384 * 512 * 2;

  wprep4_kernel<<<dim3(8, 4, 4), 256, 0, stream>>>(
      Wq, Wk, Wv, Wo, wtq, wtk, wtv, wto);
  ln_x_kernel<<<dim3(BATCH * (HW / 32)), 256, 0, stream>>>(x, ln_xg, ln_xb, xn, xnbf);
  ln_y_kernel<<<dim3(BATCH * MCTX / 4), 256, 0, stream>>>(y, ln_yg, ln_yb, ynbf);
  // q = (xn @ Wq) * 0.125 * log2(e)  (scale folded; softmax runs in exp2 domain)
  mfma_gemm<false><<<dim3(4, 128), 256, 0, stream>>>(
      xnbf, wtq, nullptr, nullptr, qbf, 16384, 512, 256, 0.1803368801111204f);
  // K + V projections; V written directly in transposed per-head layout
  mfma_gemm_kv<<<dim3(8, 32), 256, 0, stream>>>(ynbf, wtk, wtv, bv, kbf, vtb);
  attn_mfma<<<dim3(HW / 256, HEADS, BATCH), 512, 0, stream>>>(qbf, kbf, vtb, aobf);
  // out = ao @ Wo + bo + xn
  mfma_gemm<true><<<dim3(2, 128), 256, 0, stream>>>(
      aobf, wto, bo, xn, out, 16384, 256, 512, 1.f);
}